// Round 10
// baseline (8496.465 us; speedup 1.0000x reference)
//
#include <hip/hip_runtime.h>
#include <math.h>

// EncoderRNN persistent kernel, round 15 = round 14 (PASSING, 4.76ms) + two
// serial-latency cuts:
//  (A) Flags packed 16/line (u32[256] contiguous): block0's gather sweep is
//      16 CP transactions instead of 256. ONLY block0 polls flags (r10's
//      regression was everyone polling); gen broadcast poll unchanged.
//  (B) Per-wave-aligned staging, NO staging->MFMA barrier: wave wv MFMAs
//      k in [256wv,256wv+256) and now stages exactly that range itself
//      (same load count, same 64-consecutive-u64 coalescing, bit-identical
//      unpack). Wave-local LDS RAW is compiler-ordered; gl2 WAR is covered
//      by the MFMA->cell barrier + end-of-step device barrier. Each wave
//      starts MFMA when ITS sc1 loads land (no block-wide straggler wait).
//      emb path same alignment (wave w -> units [256w,256w+256), 4 lanes/row
//      x 32B contiguous -> also fixes r14's 4-way LDS-write aliasing).
//      Fallback (embP null): uniform conditional __syncthreads preserved.
// Everything else r14 verbatim. If fail/regress: revert (B) first.
// Predicted: pass, absmax 0.0001220703, dur 4.76 -> ~4.1-4.5ms,
// bank-conflict 1.34e8 -> ~1.0e8, FETCH/WRITE unchanged.

#define SEQ 1024
#define NB 32
#define NH 512
#define BH (NB*NH)
#define NV 32000
#define KP 1032   // LDS row stride in shorts = 2064 B (odd 16B slots)

typedef __attribute__((ext_vector_type(8))) short short8;
typedef __attribute__((ext_vector_type(4))) float f32x4;
typedef unsigned long long u64;

struct P {
  const int*   word;
  const float* emb;
  const float* Wih[4];   // dl = dir*2+layer: 0=fwd1,1=fwd2,2=bwd1,3=bwd2
  const float* Whh[4];
  const float* bih[4];
  const float* bhh[4];
  unsigned* flags;       // u32[256] contiguous (16 lines) - block0-only gather
  unsigned* gen;         // single 64B line - broadcast poll
  unsigned* hpk;         // [4 dl][2 par][NB][NH] u32 = (bf16hi | bf16lo<<16)
  const unsigned* embP;  // [NV][NH] u32 packed (hh | hl<<16), or null
  float* out;
};

__device__ __forceinline__ unsigned short f2bf(float x) {
  unsigned u = __float_as_uint(x);
  return (unsigned short)((u + 0x7fffu + ((u >> 16) & 1u)) >> 16);  // RNE
}
__device__ __forceinline__ float bf2f(unsigned short b) {
  return __uint_as_float(((unsigned)b) << 16);
}
__device__ __forceinline__ float sigf(float x) { return 1.0f / (1.0f + expf(-x)); }

__device__ __forceinline__ unsigned ald(const unsigned* p_) {
  return __hip_atomic_load((unsigned*)p_, __ATOMIC_RELAXED, __HIP_MEMORY_SCOPE_AGENT);
}
__device__ __forceinline__ u64 ald64(const u64* p_) {
  return __hip_atomic_load((u64*)p_, __ATOMIC_RELAXED, __HIP_MEMORY_SCOPE_AGENT);
}
__device__ __forceinline__ void ast(unsigned* p_, unsigned v) {
  __hip_atomic_store(p_, v, __ATOMIC_RELAXED, __HIP_MEMORY_SCOPE_AGENT);
}
__device__ __forceinline__ float aldf(const float* p_) {
  return __hip_atomic_load((float*)p_, __ATOMIC_RELAXED, __HIP_MEMORY_SCOPE_AGENT);
}
__device__ __forceinline__ void astf(float* p_, float v) {
  __hip_atomic_store(p_, v, __ATOMIC_RELAXED, __HIP_MEMORY_SCOPE_AGENT);
}

// Per-wave coalesced slab stage: ONE wave reads 16KB (16 rows x 128 u64 of
// its unit half) and writes bf16 hi/lo planes for exactly the k-range its
// own MFMA consumes. Per instr q: 64 consecutive u64 = 8 fully-consumed
// lines. Unpack bit-identical to r13/r14.
__device__ __forceinline__ void stage_slab_wave(const unsigned* slab,
                                                unsigned short* xhHi,
                                                unsigned short* xhLo,
                                                int L, int wvHalf, int koff) {
  const u64* s64 = (const u64*)slab;
  u64 A[32];
#pragma unroll
  for (int q = 0; q < 32; ++q) {
    const int idx = (q >> 1) * 256 + wvHalf * 128 + (q & 1) * 64 + L;
    A[q] = ald64(s64 + idx);
  }
#pragma unroll
  for (int q = 0; q < 32; ++q) {
    const int r = q >> 1;
    const int c = wvHalf * 128 + (q & 1) * 64 + L;   // u64 col -> units 2c,2c+1
    const unsigned w0 = (unsigned)A[q];
    const unsigned w1 = (unsigned)(A[q] >> 32);
    *(unsigned*)(xhHi + r * KP + koff + 2 * c) = (w0 & 0xffffu) | (w1 << 16);
    *(unsigned*)(xhLo + r * KP + koff + 2 * c) = (w0 >> 16)     | (w1 & 0xffff0000u);
  }
}

// one-time embedding fp32 -> packed u32 (hh | hl<<16); identical RNE math
__global__ void conv_embp(const float* __restrict__ e,
                          unsigned* __restrict__ pk) {
  const size_t i = ((size_t)blockIdx.x * 256 + threadIdx.x) * 8;
  float4 a = *(const float4*)(e + i);
  float4 b = *(const float4*)(e + i + 4);
  float xs[8] = {a.x, a.y, a.z, a.w, b.x, b.y, b.z, b.w};
  unsigned o[8];
#pragma unroll
  for (int q = 0; q < 8; ++q) {
    unsigned short hb = f2bf(xs[q]);
    unsigned short lb = f2bf(xs[q] - bf2f(hb));
    o[q] = (unsigned)hb | ((unsigned)lb << 16);
  }
  uint4 v0, v1;
  v0.x=o[0]; v0.y=o[1]; v0.z=o[2]; v0.w=o[3];
  v1.x=o[4]; v1.y=o[5]; v1.z=o[6]; v1.w=o[7];
  *(uint4*)(pk + i)     = v0;
  *(uint4*)(pk + i + 4) = v1;
}

__global__ __launch_bounds__(256, 1) void enc_persist(P p) {
  extern __shared__ unsigned short smem[];
  unsigned short* xhHi = smem;              // [16][KP]
  unsigned short* xhLo = smem + 16 * KP;    // [16][KP]
  float* gl2 = (float*)(smem + 32 * KP);    // [4 wv][4 gate][16 batch][20] fp32

  const int tid  = threadIdx.x;
  const int bid  = blockIdx.x;
  const int dl   = bid >> 6;
  const int dir  = dl >> 1, layer = dl & 1;
  const int r6   = bid & 63;
  const int u0   = (r6 >> 1) * 16;   // 32 unit-groups of 16
  const int b0   = (r6 & 1) * 16;    // 2 batch-halves of 16
  const int lane = tid & 63, wv = tid >> 6;   // wave wv owns kc in [8wv, 8wv+8)

  // ---- prologue: W fragments (bf16 hi/lo) for all 4 gates, this wave's K ----
  short8 aHi[32], aLo[32];   // index gg*8+kk
  {
    const int kg = (lane >> 4) * 8;
#pragma unroll
    for (int gg = 0; gg < 4; ++gg) {
      const int gr = gg * 512 + u0 + (lane & 15);   // global gate row
      const float* Wi = p.Wih[dl] + (size_t)gr * NH;
      const float* Wh = p.Whh[dl] + (size_t)gr * NH;
#pragma unroll
      for (int kk = 0; kk < 8; ++kk) {
        const int k0 = (wv * 8 + kk) * 32 + kg;
        const float* s = (k0 < 512) ? (Wi + k0) : (Wh + (k0 - 512));
        float4 v0 = *(const float4*)s;
        float4 v1 = *(const float4*)(s + 4);
        float xs[8] = {v0.x, v0.y, v0.z, v0.w, v1.x, v1.y, v1.z, v1.w};
        short8 h8, l8;
#pragma unroll
        for (int q = 0; q < 8; ++q) {
          unsigned short hb = f2bf(xs[q]);
          h8[q] = (short)hb;
          l8[q] = (short)f2bf(xs[q] - bf2f(hb));
        }
        aHi[gg * 8 + kk] = h8; aLo[gg * 8 + kk] = l8;
      }
    }
  }

  // cell thread mapping: cb = batch-local (tid>>4), cu = unit (tid&15)
  const int cu = tid & 15, cb = tid >> 4;
  const int uG = u0 + cu;
  const float bi  = p.bih[dl][uG]        + p.bhh[dl][uG];
  const float bf_ = p.bih[dl][512 + uG]  + p.bhh[dl][512 + uG];
  const float bg  = p.bih[dl][1024 + uG] + p.bhh[dl][1024 + uG];
  const float bo  = p.bih[dl][1536 + uG] + p.bhh[dl][1536 + uG];

  float c_reg = 0.f, h_reg = 0.f;

  // fallback emb staging mapping (embP null): rb = row, sr = k-slice
  const int sr = tid >> 4;
  const int rb = tid & 15;
  const int ks = sr * 64;

  // packed emb staging mapping (waves 0-1): 4 lanes/row, 32B contiguous/lane
  const int er   = lane >> 2;          // row 0..15
  const int lsub = lane & 3;           // sub-slot within row
  const int ubase = 256 * wv;          // this wave's unit range base (wv<2)

  int tk, tk_st, tk_u;
  {
    const int to0 = dir ? (SEQ - 1) : 0;
    tk    = p.word[(size_t)to0 * NB + b0 + cb];   // cell mask token
    tk_st = p.word[(size_t)to0 * NB + b0 + rb];   // fallback staging token
    tk_u  = p.word[(size_t)to0 * NB + b0 + er];   // packed staging token
  }

  const bool use_pk = (layer == 0) && (wv < 2) && (p.embP != nullptr);
  const bool do_epf = (layer == 0) && (sr < 8) && (p.embP == nullptr);
  union { float4 f[16]; uint4 u[16]; } epr;
  if (use_pk) {   // prologue prefetch for j=0 (packed)
    const unsigned* src = p.embP + (size_t)tk_u * NH + ubase + lsub * 4;
#pragma unroll
    for (int q = 0; q < 16; ++q) epr.u[q] = *(const uint4*)(src + 16 * q);
  } else if (do_epf) {  // prologue prefetch for j=0 (fallback fp32)
    const float* e = p.emb + (size_t)tk_st * NH + ks;
#pragma unroll
    for (int q = 0; q < 16; ++q) epr.f[q] = *(const float4*)(e + q * 4);
  }

  for (int j = 0; j <= SEQ; ++j) {
    const int act = layer ? (j >= 1) : (j < SEQ);
    const int t = layer ? (j - 1) : j;
    const int torig = dir ? (SEQ - 1 - t) : t;
    const int par = j & 1;

    if (act) {
      // ---- per-wave staging: wave wv fills exactly k in [256wv,256wv+256) ----
      if (wv < 2) {   // x-part
        if (layer == 0) {
          if (p.embP) {
            // unpack prefetched packed-emb registers -> LDS (bit-exact)
#pragma unroll
            for (int q = 0; q < 16; ++q) {
              const uint4 w = epr.u[q];
              const int u = ubase + lsub * 4 + 16 * q;
              uint2 hv, lv;
              hv.x = (w.x & 0xffffu) | (w.y << 16);
              hv.y = (w.z & 0xffffu) | (w.w << 16);
              lv.x = (w.x >> 16)     | (w.y & 0xffff0000u);
              lv.y = (w.z >> 16)     | (w.w & 0xffff0000u);
              *(uint2*)(xhHi + er * KP + u) = hv;
              *(uint2*)(xhLo + er * KP + u) = lv;
            }
          } else {  // fallback: convert prefetched fp32 regs (cross-wave map)
#pragma unroll
            for (int h2 = 0; h2 < 2; ++h2) {
#pragma unroll
              for (int q = 0; q < 4; ++q) {
                const float4 va = epr.f[h2 * 8 + 2 * q];
                const float4 vb = epr.f[h2 * 8 + 2 * q + 1];
                float xs[8] = {va.x, va.y, va.z, va.w, vb.x, vb.y, vb.z, vb.w};
                unsigned hw[4], lw[4];
#pragma unroll
                for (int m = 0; m < 4; ++m) {
                  unsigned short ha = f2bf(xs[2*m]);
                  unsigned short hc = f2bf(xs[2*m+1]);
                  unsigned short la = f2bf(xs[2*m]   - bf2f(ha));
                  unsigned short lc = f2bf(xs[2*m+1] - bf2f(hc));
                  hw[m] = (unsigned)ha | ((unsigned)hc << 16);
                  lw[m] = (unsigned)la | ((unsigned)lc << 16);
                }
                uint4 hv, lv;
                hv.x=hw[0]; hv.y=hw[1]; hv.z=hw[2]; hv.w=hw[3];
                lv.x=lw[0]; lv.y=lw[1]; lv.z=lw[2]; lv.w=lw[3];
                *(uint4*)(xhHi + rb * KP + ks + h2 * 32 + q * 8) = hv;
                *(uint4*)(xhLo + rb * KP + ks + h2 * 32 + q * 8) = lv;
              }
            }
          }
        } else {      // layer2 x = layer1 h: per-wave half-slab
          const unsigned* slab = p.hpk + (size_t)((dl - 1) * 2 + par) * BH
                                       + (size_t)b0 * NH;
          stage_slab_wave(slab, xhHi, xhLo, lane, wv & 1, 0);
        }
      } else {        // recurrent half: per-wave half-slab (k 512..1023)
        const unsigned* slab = p.hpk + (size_t)(dl * 2 + par) * BH
                                     + (size_t)b0 * NH;
        stage_slab_wave(slab, xhHi, xhLo, lane, wv & 1, 512);
      }
    }

    // prefetch next step's tokens (latency hides under MFMA+cell+barrier)
    int tk_nx = tk, tk_st_nx = tk_st, tk_u_nx = tk_u;
    if (j < SEQ) {
      int t_nx = layer ? j : (j + 1);
      if (t_nx > SEQ - 1) t_nx = SEQ - 1;
      const int to_nx = dir ? (SEQ - 1 - t_nx) : t_nx;
      tk_nx    = p.word[(size_t)to_nx * NB + b0 + cb];
      tk_st_nx = p.word[(size_t)to_nx * NB + b0 + rb];
      tk_u_nx  = p.word[(size_t)to_nx * NB + b0 + er];
    }

    // out-partner prefetch (r12 (ii)): partner written >=1 epoch ago.
    float out_pf = 0.f;
    size_t oi = 0;
    int do_add = 0;
    if (act && layer == 1) {
      oi = (size_t)torig * BH + (size_t)(b0 + cb) * NH + uG;
      do_add = dir ? (torig < 512) : (torig > 511);
      if (do_add) out_pf = aldf(p.out + oi);
    }

    // Staging is wave-self-consistent with the packed table -> no barrier.
    // Fallback path uses the cross-wave map -> uniform conditional barrier.
    if (!p.embP) __syncthreads();

    if (act) {
      // ---- K-split MFMA: wave wv sums kc in [8wv,8wv+8) for all 4 gates ----
      f32x4 aA[4], aBC[4];
#pragma unroll
      for (int gg = 0; gg < 4; ++gg) {
        aA[gg]  = (f32x4){0.f, 0.f, 0.f, 0.f};
        aBC[gg] = (f32x4){0.f, 0.f, 0.f, 0.f};
      }
      const unsigned short* bp = xhHi + (lane & 15) * KP + (lane >> 4) * 8;
      const unsigned short* bq = xhLo + (lane & 15) * KP + (lane >> 4) * 8;
#pragma unroll
      for (int kk = 0; kk < 8; ++kk) {
        const int kc = wv * 8 + kk;
        short8 bH = *(const short8*)(bp + kc * 32);
        short8 bL = *(const short8*)(bq + kc * 32);
#pragma unroll
        for (int gg = 0; gg < 4; ++gg) {
          aA[gg]  = __builtin_amdgcn_mfma_f32_16x16x32_bf16(aHi[gg*8+kk], bH, aA[gg],  0, 0, 0);
          aBC[gg] = __builtin_amdgcn_mfma_f32_16x16x32_bf16(aLo[gg*8+kk], bH, aBC[gg], 0, 0, 0);
          aBC[gg] = __builtin_amdgcn_mfma_f32_16x16x32_bf16(aHi[gg*8+kk], bL, aBC[gg], 0, 0, 0);
        }
      }
      // C/D (m89): col = lane&15 = batch, row = (lane>>4)*4 + reg = unit
#pragma unroll
      for (int gg = 0; gg < 4; ++gg) {
        f32x4 acc = aA[gg] + aBC[gg];
        *(f32x4*)&gl2[((wv * 4 + gg) * 16 + (lane & 15)) * 20 + (lane >> 4) * 4] = acc;
      }
    }
    __syncthreads();

    if (act) {
      // ---- fused cell: tree-sum the 4 waves' K-partials ----
#define GL2(w_,g_) gl2[(((w_) * 4 + (g_)) * 16 + cb) * 20 + cu]
      const float vi = ((GL2(0,0)+GL2(1,0)) + (GL2(2,0)+GL2(3,0))) + bi;
      const float vf = ((GL2(0,1)+GL2(1,1)) + (GL2(2,1)+GL2(3,1))) + bf_;
      const float vg = ((GL2(0,2)+GL2(1,2)) + (GL2(2,2)+GL2(3,2))) + bg;
      const float vo = ((GL2(0,3)+GL2(1,3)) + (GL2(2,3)+GL2(3,3))) + bo;
#undef GL2
      float cn = sigf(vf) * c_reg + sigf(vi) * tanhf(vg);
      float hn = sigf(vo) * tanhf(cn);
      if (tk == 1) { cn = c_reg; hn = h_reg; }
      c_reg = cn; h_reg = hn;
      const unsigned short hh = f2bf(hn);
      const unsigned short hl = f2bf(hn - bf2f(hh));
      const size_t hix = (size_t)(dl * 2 + (par ^ 1)) * BH + (size_t)(b0 + cb) * NH + uG;
      ast(p.hpk + hix, (unsigned)hh | ((unsigned)hl << 16));
      if (layer == 1) {
        // ordered by the full device barrier per step; partner prefetched
        const float v = dir ? (0.5f * hn) : hn;
        astf(p.out + oi, do_add ? (out_pf + v) : v);
      }
    }

    tk = tk_nx; tk_st = tk_st_nx; tk_u = tk_u_nx;

    // ---- flat leader device barrier (r6 topology, packed flag lines) ----
    __syncthreads();   // drains vmcnt -> all sc1 stores acked at coherence point
    if (tid == 0)
      ast(p.flags + bid, (unsigned)(j + 1));

    // issue next-step emb loads NOW; they fly during the gen-wait
    if (j + 1 < SEQ) {
      if (use_pk) {
        const unsigned* src = p.embP + (size_t)tk_u * NH + ubase + lsub * 4;
#pragma unroll
        for (int q = 0; q < 16; ++q) epr.u[q] = *(const uint4*)(src + 16 * q);
      } else if (do_epf) {
        const float* e = p.emb + (size_t)tk_st * NH + ks;
#pragma unroll
        for (int q = 0; q < 16; ++q) epr.f[q] = *(const float4*)(e + q * 4);
      }
    }

    if (bid == 0) {
      // gather: 256 threads x 1 flag, now 16 lines per sweep (was 256)
      while (ald(p.flags + tid) < (unsigned)(j + 1)) __builtin_amdgcn_s_sleep(1);
      __syncthreads();
      if (tid == 0) ast(p.gen, (unsigned)(j + 1));
    } else {
      if (tid < 64) {
        while (ald(p.gen) < (unsigned)(j + 1)) __builtin_amdgcn_s_sleep(1);
      }
      __syncthreads();
    }
  }

  // ---- epilogue: backward final carries bh1,bc1,bh2,bc2 ----
  if (dl == 2) {
    p.out[(size_t)SEQ * BH + 0 * (size_t)BH + (size_t)(b0 + cb) * NH + uG] = h_reg;
    p.out[(size_t)SEQ * BH + 1 * (size_t)BH + (size_t)(b0 + cb) * NH + uG] = c_reg;
  } else if (dl == 3) {
    p.out[(size_t)SEQ * BH + 2 * (size_t)BH + (size_t)(b0 + cb) * NH + uG] = h_reg;
    p.out[(size_t)SEQ * BH + 3 * (size_t)BH + (size_t)(b0 + cb) * NH + uG] = c_reg;
  }
}

extern "C" void kernel_launch(void* const* d_in, const int* in_sizes, int n_in,
                              void* d_out, int out_size, void* d_ws, size_t ws_size,
                              hipStream_t stream) {
  P p;
  p.word = (const int*)d_in[0];
  p.emb  = (const float*)d_in[1];
  for (int i = 0; i < 4; ++i) {
    p.Wih[i] = (const float*)d_in[2 + i * 4 + 0];
    p.Whh[i] = (const float*)d_in[2 + i * 4 + 1];
    p.bih[i] = (const float*)d_in[2 + i * 4 + 2];
    p.bhh[i] = (const float*)d_in[2 + i * 4 + 3];
  }
  unsigned char* ws = (unsigned char*)d_ws;
  p.flags = (unsigned*)ws;                       // u32[256] packed (1 KB used)
  p.gen   = (unsigned*)(ws + 16384);             // one 64B line
  p.hpk   = (unsigned*)(ws + 16448);             // 512 KB packed h
  const size_t embOff  = (size_t)1 << 20;        // 1 MB
  const size_t embBytes = (size_t)NV * NH * 4;   // 62.5 MB packed table
  if (ws_size >= embOff + embBytes) {
    p.embP = (const unsigned*)(ws + embOff);
  } else {
    p.embP = nullptr;
  }
  p.out = (float*)d_out;

  hipMemsetAsync(d_ws, 0, 16448 + (size_t)8 * BH * 4, stream);

  if (p.embP) {
    // NV*NH = 16,384,000 elems, 8/thread -> 8000 blocks x 256
    hipLaunchKernelGGL(conv_embp, dim3(8000), dim3(256), 0, stream,
                       p.emb, (unsigned*)p.embP);
  }

  // used: 32*KP*2 + 4*4*16*20*4 = 86528 B; request 88 KB to keep 1 block/CU
  const int smem = 90112;
  hipFuncSetAttribute(reinterpret_cast<const void*>(enc_persist),
                      hipFuncAttributeMaxDynamicSharedMemorySize, smem);
  hipLaunchKernelGGL(enc_persist, dim3(256), dim3(256), smem, stream, p);
}

// Round 11
// 8318.805 us; speedup vs baseline: 1.0214x; 1.0214x over previous
//
#include <hip/hip_runtime.h>
#include <math.h>

// EncoderRNN persistent kernel, round 16 = round 15 with (A) REVERTED.
// r15 post-mortem: packed flags (16 writers + 1 poller per line) recreated
// r11's poll-a-hot-line anti-pattern; regression magnitude (+4us/step)
// matched r11's. Flag layout back to r6/r14: ONE flag per 64B line, single
// writer per line, block0 sole poller, gen single-line broadcast.
// KEPT from r15 (B): per-wave-aligned staging with NO staging->MFMA barrier:
// wave wv stages and MFMAs exactly k in [256wv,256wv+256); wave-local LDS
// RAW is hw/compiler-ordered; gl2 WAR covered by MFMA->cell barrier +
// end-of-step device barrier. This round doubles as (B)'s bisection: if dur
// is still >4.76ms, (B) also hurts and r17 reverts it to r14's block map.
// Predicted: pass, absmax 0.0001220703, dur 8.50 -> ~4.2-4.7ms,
// MfmaUtil ~13-14, VALUBusy ~20-22, bank-conflict ~1.0-1.3e8.

#define SEQ 1024
#define NB 32
#define NH 512
#define BH (NB*NH)
#define NV 32000
#define KP 1032   // LDS row stride in shorts = 2064 B (odd 16B slots)

typedef __attribute__((ext_vector_type(8))) short short8;
typedef __attribute__((ext_vector_type(4))) float f32x4;
typedef unsigned long long u64;

struct P {
  const int*   word;
  const float* emb;
  const float* Wih[4];   // dl = dir*2+layer: 0=fwd1,1=fwd2,2=bwd1,3=bwd2
  const float* Whh[4];
  const float* bih[4];
  const float* bhh[4];
  unsigned* flags;       // 256 slots, stride 16 u32 (one 64B line each)
  unsigned* gen;         // single 64B line - broadcast poll
  unsigned* hpk;         // [4 dl][2 par][NB][NH] u32 = (bf16hi | bf16lo<<16)
  const unsigned* embP;  // [NV][NH] u32 packed (hh | hl<<16), or null
  float* out;
};

__device__ __forceinline__ unsigned short f2bf(float x) {
  unsigned u = __float_as_uint(x);
  return (unsigned short)((u + 0x7fffu + ((u >> 16) & 1u)) >> 16);  // RNE
}
__device__ __forceinline__ float bf2f(unsigned short b) {
  return __uint_as_float(((unsigned)b) << 16);
}
__device__ __forceinline__ float sigf(float x) { return 1.0f / (1.0f + expf(-x)); }

__device__ __forceinline__ unsigned ald(const unsigned* p_) {
  return __hip_atomic_load((unsigned*)p_, __ATOMIC_RELAXED, __HIP_MEMORY_SCOPE_AGENT);
}
__device__ __forceinline__ u64 ald64(const u64* p_) {
  return __hip_atomic_load((u64*)p_, __ATOMIC_RELAXED, __HIP_MEMORY_SCOPE_AGENT);
}
__device__ __forceinline__ void ast(unsigned* p_, unsigned v) {
  __hip_atomic_store(p_, v, __ATOMIC_RELAXED, __HIP_MEMORY_SCOPE_AGENT);
}
__device__ __forceinline__ float aldf(const float* p_) {
  return __hip_atomic_load((float*)p_, __ATOMIC_RELAXED, __HIP_MEMORY_SCOPE_AGENT);
}
__device__ __forceinline__ void astf(float* p_, float v) {
  __hip_atomic_store(p_, v, __ATOMIC_RELAXED, __HIP_MEMORY_SCOPE_AGENT);
}

// Per-wave coalesced slab stage (r15 (B)): ONE wave reads 16KB (16 rows x
// 128 u64 of its unit half) for exactly the k-range its own MFMA consumes.
// Per instr q: 64 consecutive u64 = 8 fully-consumed lines.
__device__ __forceinline__ void stage_slab_wave(const unsigned* slab,
                                                unsigned short* xhHi,
                                                unsigned short* xhLo,
                                                int L, int wvHalf, int koff) {
  const u64* s64 = (const u64*)slab;
  u64 A[32];
#pragma unroll
  for (int q = 0; q < 32; ++q) {
    const int idx = (q >> 1) * 256 + wvHalf * 128 + (q & 1) * 64 + L;
    A[q] = ald64(s64 + idx);
  }
#pragma unroll
  for (int q = 0; q < 32; ++q) {
    const int r = q >> 1;
    const int c = wvHalf * 128 + (q & 1) * 64 + L;   // u64 col -> units 2c,2c+1
    const unsigned w0 = (unsigned)A[q];
    const unsigned w1 = (unsigned)(A[q] >> 32);
    *(unsigned*)(xhHi + r * KP + koff + 2 * c) = (w0 & 0xffffu) | (w1 << 16);
    *(unsigned*)(xhLo + r * KP + koff + 2 * c) = (w0 >> 16)     | (w1 & 0xffff0000u);
  }
}

// one-time embedding fp32 -> packed u32 (hh | hl<<16); identical RNE math
__global__ void conv_embp(const float* __restrict__ e,
                          unsigned* __restrict__ pk) {
  const size_t i = ((size_t)blockIdx.x * 256 + threadIdx.x) * 8;
  float4 a = *(const float4*)(e + i);
  float4 b = *(const float4*)(e + i + 4);
  float xs[8] = {a.x, a.y, a.z, a.w, b.x, b.y, b.z, b.w};
  unsigned o[8];
#pragma unroll
  for (int q = 0; q < 8; ++q) {
    unsigned short hb = f2bf(xs[q]);
    unsigned short lb = f2bf(xs[q] - bf2f(hb));
    o[q] = (unsigned)hb | ((unsigned)lb << 16);
  }
  uint4 v0, v1;
  v0.x=o[0]; v0.y=o[1]; v0.z=o[2]; v0.w=o[3];
  v1.x=o[4]; v1.y=o[5]; v1.z=o[6]; v1.w=o[7];
  *(uint4*)(pk + i)     = v0;
  *(uint4*)(pk + i + 4) = v1;
}

__global__ __launch_bounds__(256, 1) void enc_persist(P p) {
  extern __shared__ unsigned short smem[];
  unsigned short* xhHi = smem;              // [16][KP]
  unsigned short* xhLo = smem + 16 * KP;    // [16][KP]
  float* gl2 = (float*)(smem + 32 * KP);    // [4 wv][4 gate][16 batch][20] fp32

  const int tid  = threadIdx.x;
  const int bid  = blockIdx.x;
  const int dl   = bid >> 6;
  const int dir  = dl >> 1, layer = dl & 1;
  const int r6   = bid & 63;
  const int u0   = (r6 >> 1) * 16;   // 32 unit-groups of 16
  const int b0   = (r6 & 1) * 16;    // 2 batch-halves of 16
  const int lane = tid & 63, wv = tid >> 6;   // wave wv owns kc in [8wv, 8wv+8)

  // ---- prologue: W fragments (bf16 hi/lo) for all 4 gates, this wave's K ----
  short8 aHi[32], aLo[32];   // index gg*8+kk
  {
    const int kg = (lane >> 4) * 8;
#pragma unroll
    for (int gg = 0; gg < 4; ++gg) {
      const int gr = gg * 512 + u0 + (lane & 15);   // global gate row
      const float* Wi = p.Wih[dl] + (size_t)gr * NH;
      const float* Wh = p.Whh[dl] + (size_t)gr * NH;
#pragma unroll
      for (int kk = 0; kk < 8; ++kk) {
        const int k0 = (wv * 8 + kk) * 32 + kg;
        const float* s = (k0 < 512) ? (Wi + k0) : (Wh + (k0 - 512));
        float4 v0 = *(const float4*)s;
        float4 v1 = *(const float4*)(s + 4);
        float xs[8] = {v0.x, v0.y, v0.z, v0.w, v1.x, v1.y, v1.z, v1.w};
        short8 h8, l8;
#pragma unroll
        for (int q = 0; q < 8; ++q) {
          unsigned short hb = f2bf(xs[q]);
          h8[q] = (short)hb;
          l8[q] = (short)f2bf(xs[q] - bf2f(hb));
        }
        aHi[gg * 8 + kk] = h8; aLo[gg * 8 + kk] = l8;
      }
    }
  }

  // cell thread mapping: cb = batch-local (tid>>4), cu = unit (tid&15)
  const int cu = tid & 15, cb = tid >> 4;
  const int uG = u0 + cu;
  const float bi  = p.bih[dl][uG]        + p.bhh[dl][uG];
  const float bf_ = p.bih[dl][512 + uG]  + p.bhh[dl][512 + uG];
  const float bg  = p.bih[dl][1024 + uG] + p.bhh[dl][1024 + uG];
  const float bo  = p.bih[dl][1536 + uG] + p.bhh[dl][1536 + uG];

  float c_reg = 0.f, h_reg = 0.f;

  // fallback emb staging mapping (embP null): rb = row, sr = k-slice
  const int sr = tid >> 4;
  const int rb = tid & 15;
  const int ks = sr * 64;

  // packed emb staging mapping (waves 0-1): 4 lanes/row, 32B contiguous/lane
  const int er   = lane >> 2;          // row 0..15
  const int lsub = lane & 3;           // sub-slot within row
  const int ubase = 256 * wv;          // this wave's unit range base (wv<2)

  int tk, tk_st, tk_u;
  {
    const int to0 = dir ? (SEQ - 1) : 0;
    tk    = p.word[(size_t)to0 * NB + b0 + cb];   // cell mask token
    tk_st = p.word[(size_t)to0 * NB + b0 + rb];   // fallback staging token
    tk_u  = p.word[(size_t)to0 * NB + b0 + er];   // packed staging token
  }

  const bool use_pk = (layer == 0) && (wv < 2) && (p.embP != nullptr);
  const bool do_epf = (layer == 0) && (sr < 8) && (p.embP == nullptr);
  union { float4 f[16]; uint4 u[16]; } epr;
  if (use_pk) {   // prologue prefetch for j=0 (packed)
    const unsigned* src = p.embP + (size_t)tk_u * NH + ubase + lsub * 4;
#pragma unroll
    for (int q = 0; q < 16; ++q) epr.u[q] = *(const uint4*)(src + 16 * q);
  } else if (do_epf) {  // prologue prefetch for j=0 (fallback fp32)
    const float* e = p.emb + (size_t)tk_st * NH + ks;
#pragma unroll
    for (int q = 0; q < 16; ++q) epr.f[q] = *(const float4*)(e + q * 4);
  }

  for (int j = 0; j <= SEQ; ++j) {
    const int act = layer ? (j >= 1) : (j < SEQ);
    const int t = layer ? (j - 1) : j;
    const int torig = dir ? (SEQ - 1 - t) : t;
    const int par = j & 1;

    if (act) {
      // ---- per-wave staging: wave wv fills exactly k in [256wv,256wv+256) ----
      if (wv < 2) {   // x-part
        if (layer == 0) {
          if (p.embP) {
            // unpack prefetched packed-emb registers -> LDS (bit-exact)
#pragma unroll
            for (int q = 0; q < 16; ++q) {
              const uint4 w = epr.u[q];
              const int u = ubase + lsub * 4 + 16 * q;
              uint2 hv, lv;
              hv.x = (w.x & 0xffffu) | (w.y << 16);
              hv.y = (w.z & 0xffffu) | (w.w << 16);
              lv.x = (w.x >> 16)     | (w.y & 0xffff0000u);
              lv.y = (w.z >> 16)     | (w.w & 0xffff0000u);
              *(uint2*)(xhHi + er * KP + u) = hv;
              *(uint2*)(xhLo + er * KP + u) = lv;
            }
          } else {  // fallback: convert prefetched fp32 regs (cross-wave map)
#pragma unroll
            for (int h2 = 0; h2 < 2; ++h2) {
#pragma unroll
              for (int q = 0; q < 4; ++q) {
                const float4 va = epr.f[h2 * 8 + 2 * q];
                const float4 vb = epr.f[h2 * 8 + 2 * q + 1];
                float xs[8] = {va.x, va.y, va.z, va.w, vb.x, vb.y, vb.z, vb.w};
                unsigned hw[4], lw[4];
#pragma unroll
                for (int m = 0; m < 4; ++m) {
                  unsigned short ha = f2bf(xs[2*m]);
                  unsigned short hc = f2bf(xs[2*m+1]);
                  unsigned short la = f2bf(xs[2*m]   - bf2f(ha));
                  unsigned short lc = f2bf(xs[2*m+1] - bf2f(hc));
                  hw[m] = (unsigned)ha | ((unsigned)hc << 16);
                  lw[m] = (unsigned)la | ((unsigned)lc << 16);
                }
                uint4 hv, lv;
                hv.x=hw[0]; hv.y=hw[1]; hv.z=hw[2]; hv.w=hw[3];
                lv.x=lw[0]; lv.y=lw[1]; lv.z=lw[2]; lv.w=lw[3];
                *(uint4*)(xhHi + rb * KP + ks + h2 * 32 + q * 8) = hv;
                *(uint4*)(xhLo + rb * KP + ks + h2 * 32 + q * 8) = lv;
              }
            }
          }
        } else {      // layer2 x = layer1 h: per-wave half-slab
          const unsigned* slab = p.hpk + (size_t)((dl - 1) * 2 + par) * BH
                                       + (size_t)b0 * NH;
          stage_slab_wave(slab, xhHi, xhLo, lane, wv & 1, 0);
        }
      } else {        // recurrent half: per-wave half-slab (k 512..1023)
        const unsigned* slab = p.hpk + (size_t)(dl * 2 + par) * BH
                                     + (size_t)b0 * NH;
        stage_slab_wave(slab, xhHi, xhLo, lane, wv & 1, 512);
      }
    }

    // prefetch next step's tokens (latency hides under MFMA+cell+barrier)
    int tk_nx = tk, tk_st_nx = tk_st, tk_u_nx = tk_u;
    if (j < SEQ) {
      int t_nx = layer ? j : (j + 1);
      if (t_nx > SEQ - 1) t_nx = SEQ - 1;
      const int to_nx = dir ? (SEQ - 1 - t_nx) : t_nx;
      tk_nx    = p.word[(size_t)to_nx * NB + b0 + cb];
      tk_st_nx = p.word[(size_t)to_nx * NB + b0 + rb];
      tk_u_nx  = p.word[(size_t)to_nx * NB + b0 + er];
    }

    // out-partner prefetch (r12 (ii)): partner written >=1 epoch ago.
    float out_pf = 0.f;
    size_t oi = 0;
    int do_add = 0;
    if (act && layer == 1) {
      oi = (size_t)torig * BH + (size_t)(b0 + cb) * NH + uG;
      do_add = dir ? (torig < 512) : (torig > 511);
      if (do_add) out_pf = aldf(p.out + oi);
    }

    // Staging is wave-self-consistent with the packed table -> no barrier.
    // Fallback path uses the cross-wave map -> uniform conditional barrier.
    if (!p.embP) __syncthreads();

    if (act) {
      // ---- K-split MFMA: wave wv sums kc in [8wv,8wv+8) for all 4 gates ----
      f32x4 aA[4], aBC[4];
#pragma unroll
      for (int gg = 0; gg < 4; ++gg) {
        aA[gg]  = (f32x4){0.f, 0.f, 0.f, 0.f};
        aBC[gg] = (f32x4){0.f, 0.f, 0.f, 0.f};
      }
      const unsigned short* bp = xhHi + (lane & 15) * KP + (lane >> 4) * 8;
      const unsigned short* bq = xhLo + (lane & 15) * KP + (lane >> 4) * 8;
#pragma unroll
      for (int kk = 0; kk < 8; ++kk) {
        const int kc = wv * 8 + kk;
        short8 bH = *(const short8*)(bp + kc * 32);
        short8 bL = *(const short8*)(bq + kc * 32);
#pragma unroll
        for (int gg = 0; gg < 4; ++gg) {
          aA[gg]  = __builtin_amdgcn_mfma_f32_16x16x32_bf16(aHi[gg*8+kk], bH, aA[gg],  0, 0, 0);
          aBC[gg] = __builtin_amdgcn_mfma_f32_16x16x32_bf16(aLo[gg*8+kk], bH, aBC[gg], 0, 0, 0);
          aBC[gg] = __builtin_amdgcn_mfma_f32_16x16x32_bf16(aHi[gg*8+kk], bL, aBC[gg], 0, 0, 0);
        }
      }
      // C/D (m89): col = lane&15 = batch, row = (lane>>4)*4 + reg = unit
#pragma unroll
      for (int gg = 0; gg < 4; ++gg) {
        f32x4 acc = aA[gg] + aBC[gg];
        *(f32x4*)&gl2[((wv * 4 + gg) * 16 + (lane & 15)) * 20 + (lane >> 4) * 4] = acc;
      }
    }
    __syncthreads();

    if (act) {
      // ---- fused cell: tree-sum the 4 waves' K-partials ----
#define GL2(w_,g_) gl2[(((w_) * 4 + (g_)) * 16 + cb) * 20 + cu]
      const float vi = ((GL2(0,0)+GL2(1,0)) + (GL2(2,0)+GL2(3,0))) + bi;
      const float vf = ((GL2(0,1)+GL2(1,1)) + (GL2(2,1)+GL2(3,1))) + bf_;
      const float vg = ((GL2(0,2)+GL2(1,2)) + (GL2(2,2)+GL2(3,2))) + bg;
      const float vo = ((GL2(0,3)+GL2(1,3)) + (GL2(2,3)+GL2(3,3))) + bo;
#undef GL2
      float cn = sigf(vf) * c_reg + sigf(vi) * tanhf(vg);
      float hn = sigf(vo) * tanhf(cn);
      if (tk == 1) { cn = c_reg; hn = h_reg; }
      c_reg = cn; h_reg = hn;
      const unsigned short hh = f2bf(hn);
      const unsigned short hl = f2bf(hn - bf2f(hh));
      const size_t hix = (size_t)(dl * 2 + (par ^ 1)) * BH + (size_t)(b0 + cb) * NH + uG;
      ast(p.hpk + hix, (unsigned)hh | ((unsigned)hl << 16));
      if (layer == 1) {
        // ordered by the full device barrier per step; partner prefetched
        const float v = dir ? (0.5f * hn) : hn;
        astf(p.out + oi, do_add ? (out_pf + v) : v);
      }
    }

    tk = tk_nx; tk_st = tk_st_nx; tk_u = tk_u_nx;

    // ---- flat leader device barrier (r6 verbatim: 1 writer + 1 poller/line) ----
    __syncthreads();   // drains vmcnt -> all sc1 stores acked at coherence point
    if (tid == 0)
      ast(p.flags + (size_t)bid * 16, (unsigned)(j + 1));

    // issue next-step emb loads NOW; they fly during the gen-wait
    if (j + 1 < SEQ) {
      if (use_pk) {
        const unsigned* src = p.embP + (size_t)tk_u * NH + ubase + lsub * 4;
#pragma unroll
        for (int q = 0; q < 16; ++q) epr.u[q] = *(const uint4*)(src + 16 * q);
      } else if (do_epf) {
        const float* e = p.emb + (size_t)tk_st * NH + ks;
#pragma unroll
        for (int q = 0; q < 16; ++q) epr.f[q] = *(const float4*)(e + q * 4);
      }
    }

    if (bid == 0) {
      unsigned* f = p.flags + (size_t)tid * 16;
      while (ald(f) < (unsigned)(j + 1)) __builtin_amdgcn_s_sleep(1);
      __syncthreads();
      if (tid == 0) ast(p.gen, (unsigned)(j + 1));
    } else {
      if (tid < 64) {
        while (ald(p.gen) < (unsigned)(j + 1)) __builtin_amdgcn_s_sleep(1);
      }
      __syncthreads();
    }
  }

  // ---- epilogue: backward final carries bh1,bc1,bh2,bc2 ----
  if (dl == 2) {
    p.out[(size_t)SEQ * BH + 0 * (size_t)BH + (size_t)(b0 + cb) * NH + uG] = h_reg;
    p.out[(size_t)SEQ * BH + 1 * (size_t)BH + (size_t)(b0 + cb) * NH + uG] = c_reg;
  } else if (dl == 3) {
    p.out[(size_t)SEQ * BH + 2 * (size_t)BH + (size_t)(b0 + cb) * NH + uG] = h_reg;
    p.out[(size_t)SEQ * BH + 3 * (size_t)BH + (size_t)(b0 + cb) * NH + uG] = c_reg;
  }
}

extern "C" void kernel_launch(void* const* d_in, const int* in_sizes, int n_in,
                              void* d_out, int out_size, void* d_ws, size_t ws_size,
                              hipStream_t stream) {
  P p;
  p.word = (const int*)d_in[0];
  p.emb  = (const float*)d_in[1];
  for (int i = 0; i < 4; ++i) {
    p.Wih[i] = (const float*)d_in[2 + i * 4 + 0];
    p.Whh[i] = (const float*)d_in[2 + i * 4 + 1];
    p.bih[i] = (const float*)d_in[2 + i * 4 + 2];
    p.bhh[i] = (const float*)d_in[2 + i * 4 + 3];
  }
  unsigned char* ws = (unsigned char*)d_ws;
  p.flags = (unsigned*)ws;                       // 16 KB (256 x 64B slots)
  p.gen   = (unsigned*)(ws + 16384);             // one 64B line
  p.hpk   = (unsigned*)(ws + 16448);             // 512 KB packed h
  const size_t embOff  = (size_t)1 << 20;        // 1 MB
  const size_t embBytes = (size_t)NV * NH * 4;   // 62.5 MB packed table
  if (ws_size >= embOff + embBytes) {
    p.embP = (const unsigned*)(ws + embOff);
  } else {
    p.embP = nullptr;
  }
  p.out = (float*)d_out;

  hipMemsetAsync(d_ws, 0, 16448 + (size_t)8 * BH * 4, stream);

  if (p.embP) {
    // NV*NH = 16,384,000 elems, 8/thread -> 8000 blocks x 256
    hipLaunchKernelGGL(conv_embp, dim3(8000), dim3(256), 0, stream,
                       p.emb, (unsigned*)p.embP);
  }

  // used: 32*KP*2 + 4*4*16*20*4 = 86528 B; request 88 KB to keep 1 block/CU
  const int smem = 90112;
  hipFuncSetAttribute(reinterpret_cast<const void*>(enc_persist),
                      hipFuncAttributeMaxDynamicSharedMemorySize, smem);
  hipLaunchKernelGGL(enc_persist, dim3(256), dim3(256), smem, stream, p);
}

// Round 12
// 4729.481 us; speedup vs baseline: 1.7965x; 1.7589x over previous
//
#include <hip/hip_runtime.h>
#include <math.h>

// EncoderRNN persistent kernel, round 17 = r14 RESTORED (4.76ms proven; r15/16's
// (B) per-wave barrier-free staging retired -- bisected as the 2x regression)
// + ONE subsystem change: direction-decoupled barrier via SPLIT OUTPUT BUFFERS.
//  - fwd layer1 stores hn -> out; bwd layer1 stores 0.5*hn -> bwd ws buffer.
//    NO out reads/RMW in the persistent kernel. A stream-ordered merge kernel
//    (out[i] += bwd[i], 16.7M floats, ~40us) runs after. fp32 add commutes
//    bitwise -> absmax identical to r14.
//  - With zero cross-direction data flow, the barrier splits into 4
//    independent (dir, batch-half) domains of 64 blocks. Each domain is an
//    exact r6-topology instance: single-writer flag lines, leader-gather of
//    64 lines, single-writer gen line broadcast-polled (every contention
//    pattern individually proven; r10/r11/r15 anti-patterns avoided).
//    r7/r8's corruption mechanism (out-RMW 1-step skew margin at torig=
//    511/512) is removed BY CONSTRUCTION (no cross-dir reads at all).
//  - Domain-locality audit: h slabs read only own b0-half of own dl-pair;
//    word/emb/embP read-only; epilogue carries untouched by merge.
//  - ws-guarded: ws < 129MB -> p.bwd=null -> exact r14 single-domain RMW path.
// Predicted: pass, absmax 0.0001220703, dur -> ~3.6-4.2ms (split) / ~4.76
// (fallback), MfmaUtil ~15-17, VALUBusy ~24-26, bank-conflict ~1.34e8.

#define SEQ 1024
#define NB 32
#define NH 512
#define BH (NB*NH)
#define NV 32000
#define KP 1032   // LDS row stride in shorts = 2064 B (odd 16B slots)

typedef __attribute__((ext_vector_type(8))) short short8;
typedef __attribute__((ext_vector_type(4))) float f32x4;
typedef unsigned long long u64;

struct P {
  const int*   word;
  const float* emb;
  const float* Wih[4];   // dl = dir*2+layer: 0=fwd1,1=fwd2,2=bwd1,3=bwd2
  const float* Whh[4];
  const float* bih[4];
  const float* bhh[4];
  unsigned* flags;       // 256 slots, stride 16 u32 (one 64B line each)
  unsigned* gen;         // 4 lines (one per domain; fallback uses line 0)
  unsigned* hpk;         // [4 dl][2 par][NB][NH] u32 = (bf16hi | bf16lo<<16)
  const unsigned* embP;  // [NV][NH] u32 packed (hh | hl<<16), or null
  float* out;
  float* bwd;            // bwd-direction partial buffer (or null = fallback)
};

__device__ __forceinline__ unsigned short f2bf(float x) {
  unsigned u = __float_as_uint(x);
  return (unsigned short)((u + 0x7fffu + ((u >> 16) & 1u)) >> 16);  // RNE
}
__device__ __forceinline__ float bf2f(unsigned short b) {
  return __uint_as_float(((unsigned)b) << 16);
}
__device__ __forceinline__ float sigf(float x) { return 1.0f / (1.0f + expf(-x)); }

__device__ __forceinline__ unsigned ald(const unsigned* p_) {
  return __hip_atomic_load((unsigned*)p_, __ATOMIC_RELAXED, __HIP_MEMORY_SCOPE_AGENT);
}
__device__ __forceinline__ u64 ald64(const u64* p_) {
  return __hip_atomic_load((u64*)p_, __ATOMIC_RELAXED, __HIP_MEMORY_SCOPE_AGENT);
}
__device__ __forceinline__ void ast(unsigned* p_, unsigned v) {
  __hip_atomic_store(p_, v, __ATOMIC_RELAXED, __HIP_MEMORY_SCOPE_AGENT);
}
__device__ __forceinline__ float aldf(const float* p_) {
  return __hip_atomic_load((float*)p_, __ATOMIC_RELAXED, __HIP_MEMORY_SCOPE_AGENT);
}
__device__ __forceinline__ void astf(float* p_, float v) {
  __hip_atomic_store(p_, v, __ATOMIC_RELAXED, __HIP_MEMORY_SCOPE_AGENT);
}

// Coalesced slab stage (r13/r14 proven): wave-PAIR (128 lanes) reads a 32KB
// contiguous slab (16 rows x 512 packed u32) -> bf16 hi/lo planes in LDS.
__device__ __forceinline__ void stage_slab(const unsigned* slab,
                                           unsigned short* xhHi,
                                           unsigned short* xhLo,
                                           int Lpair, int koff) {
  const u64* s64 = (const u64*)slab;
  u64 A[32];
#pragma unroll
  for (int q = 0; q < 32; ++q) A[q] = ald64(s64 + Lpair + q * 128);
#pragma unroll
  for (int q = 0; q < 32; ++q) {
    const int r = q >> 1;                    // batch row 0..15
    const int c = (q & 1) * 128 + Lpair;     // u64 col 0..255 -> units 2c,2c+1
    const unsigned w0 = (unsigned)A[q];
    const unsigned w1 = (unsigned)(A[q] >> 32);
    *(unsigned*)(xhHi + r * KP + koff + 2 * c) = (w0 & 0xffffu) | (w1 << 16);
    *(unsigned*)(xhLo + r * KP + koff + 2 * c) = (w0 >> 16)     | (w1 & 0xffff0000u);
  }
}

// one-time embedding fp32 -> packed u32 (hh | hl<<16); identical RNE math
__global__ void conv_embp(const float* __restrict__ e,
                          unsigned* __restrict__ pk) {
  const size_t i = ((size_t)blockIdx.x * 256 + threadIdx.x) * 8;
  float4 a = *(const float4*)(e + i);
  float4 b = *(const float4*)(e + i + 4);
  float xs[8] = {a.x, a.y, a.z, a.w, b.x, b.y, b.z, b.w};
  unsigned o[8];
#pragma unroll
  for (int q = 0; q < 8; ++q) {
    unsigned short hb = f2bf(xs[q]);
    unsigned short lb = f2bf(xs[q] - bf2f(hb));
    o[q] = (unsigned)hb | ((unsigned)lb << 16);
  }
  uint4 v0, v1;
  v0.x=o[0]; v0.y=o[1]; v0.z=o[2]; v0.w=o[3];
  v1.x=o[4]; v1.y=o[5]; v1.z=o[6]; v1.w=o[7];
  *(uint4*)(pk + i)     = v0;
  *(uint4*)(pk + i + 4) = v1;
}

// post-pass: out[i] += bwd[i] over torig in [0,SEQ). Same two-term fp32 add
// as r14's ordered RMW (add commutes bitwise) -> absmax identical.
__global__ void merge_out(float* __restrict__ out, const float* __restrict__ bwd) {
  const size_t i = ((size_t)blockIdx.x * 256 + threadIdx.x) * 4;
  float4 a = *(const float4*)(out + i);
  const float4 b = *(const float4*)(bwd + i);
  a.x += b.x; a.y += b.y; a.z += b.z; a.w += b.w;
  *(float4*)(out + i) = a;
}

__global__ __launch_bounds__(256, 1) void enc_persist(P p) {
  extern __shared__ unsigned short smem[];
  unsigned short* xhHi = smem;              // [16][KP]
  unsigned short* xhLo = smem + 16 * KP;    // [16][KP]
  float* gl2 = (float*)(smem + 32 * KP);    // [4 wv][4 gate][16 batch][20] fp32

  const int tid  = threadIdx.x;
  const int bid  = blockIdx.x;
  const int dl   = bid >> 6;
  const int dir  = dl >> 1, layer = dl & 1;
  const int r6   = bid & 63;
  const int u0   = (r6 >> 1) * 16;   // 32 unit-groups of 16
  const int b0   = (r6 & 1) * 16;    // 2 batch-halves of 16
  const int lane = tid & 63, wv = tid >> 6;   // wave wv owns kc in [8wv, 8wv+8)

  // barrier domain (split mode): (dir, batch-half) = exact dependency closure
  const int dom  = p.bwd ? (dir * 2 + (r6 & 1)) : 0;
  const int lid  = p.bwd ? (layer * 32 + (r6 >> 1)) : bid;
  unsigned* genp = p.gen + dom * 16;
  const bool leader = (lid == 0);
  const int dsz  = p.bwd ? 64 : 256;

  // ---- prologue: W fragments (bf16 hi/lo) for all 4 gates, this wave's K ----
  short8 aHi[32], aLo[32];   // index gg*8+kk
  {
    const int kg = (lane >> 4) * 8;
#pragma unroll
    for (int gg = 0; gg < 4; ++gg) {
      const int gr = gg * 512 + u0 + (lane & 15);   // global gate row
      const float* Wi = p.Wih[dl] + (size_t)gr * NH;
      const float* Wh = p.Whh[dl] + (size_t)gr * NH;
#pragma unroll
      for (int kk = 0; kk < 8; ++kk) {
        const int k0 = (wv * 8 + kk) * 32 + kg;
        const float* s = (k0 < 512) ? (Wi + k0) : (Wh + (k0 - 512));
        float4 v0 = *(const float4*)s;
        float4 v1 = *(const float4*)(s + 4);
        float xs[8] = {v0.x, v0.y, v0.z, v0.w, v1.x, v1.y, v1.z, v1.w};
        short8 h8, l8;
#pragma unroll
        for (int q = 0; q < 8; ++q) {
          unsigned short hb = f2bf(xs[q]);
          h8[q] = (short)hb;
          l8[q] = (short)f2bf(xs[q] - bf2f(hb));
        }
        aHi[gg * 8 + kk] = h8; aLo[gg * 8 + kk] = l8;
      }
    }
  }

  // cell thread mapping: cb = batch-local (tid>>4), cu = unit (tid&15)
  const int cu = tid & 15, cb = tid >> 4;
  const int uG = u0 + cu;
  const float bi  = p.bih[dl][uG]        + p.bhh[dl][uG];
  const float bf_ = p.bih[dl][512 + uG]  + p.bhh[dl][512 + uG];
  const float bg  = p.bih[dl][1024 + uG] + p.bhh[dl][1024 + uG];
  const float bo  = p.bih[dl][1536 + uG] + p.bhh[dl][1536 + uG];

  float c_reg = 0.f, h_reg = 0.f;

  // fallback emb staging mapping (embP null): rb = row, sr = k-slice
  const int sr = tid >> 4;
  const int rb = tid & 15;
  const int ks = sr * 64;

  // packed emb staging mapping (waves 0-1): rp = row (tid>>3), lp = tid&7
  const int rp = tid >> 3;     // 0..15 for tid<128
  const int lp = tid & 7;

  int tk, tk_st, tk_pk;
  {
    const int to0 = dir ? (SEQ - 1) : 0;
    tk    = p.word[(size_t)to0 * NB + b0 + cb];   // cell mask token
    tk_st = p.word[(size_t)to0 * NB + b0 + rb];   // fallback staging token
    tk_pk = p.word[(size_t)to0 * NB + b0 + (rp & 15)]; // packed staging token
  }

  const bool use_pk = (layer == 0) && (tid < 128) && (p.embP != nullptr);
  const bool do_epf = (layer == 0) && (sr < 8) && (p.embP == nullptr);
  union { float4 f[16]; uint4 u[16]; } epr;
  if (use_pk) {   // prologue prefetch for j=0 (packed)
    const uint4* src = (const uint4*)(p.embP + (size_t)tk_pk * NH);
#pragma unroll
    for (int q = 0; q < 16; ++q) epr.u[q] = src[lp + q * 8];
  } else if (do_epf) {  // prologue prefetch for j=0 (fallback fp32)
    const float* e = p.emb + (size_t)tk_st * NH + ks;
#pragma unroll
    for (int q = 0; q < 16; ++q) epr.f[q] = *(const float4*)(e + q * 4);
  }

  for (int j = 0; j <= SEQ; ++j) {
    const int act = layer ? (j >= 1) : (j < SEQ);
    const int t = layer ? (j - 1) : j;
    const int torig = dir ? (SEQ - 1 - t) : t;
    const int par = j & 1;

    if (act) {
      // ---- stage one row-slice of [x(512);h(512)] bf16 hi/lo into LDS ----
      if (wv < 2) {   // x-part, k in [0,512)  (wave-pair 0, uniform)
        if (layer == 0) {
          if (p.embP) {
            // unpack prefetched packed-emb registers -> LDS (bit-exact)
#pragma unroll
            for (int q = 0; q < 16; ++q) {
              const uint4 w = epr.u[q];
              const int u = 4 * (lp + q * 8);   // unit 0..508
              uint2 hv, lv;
              hv.x = (w.x & 0xffffu) | (w.y << 16);
              hv.y = (w.z & 0xffffu) | (w.w << 16);
              lv.x = (w.x >> 16)     | (w.y & 0xffff0000u);
              lv.y = (w.z >> 16)     | (w.w & 0xffff0000u);
              *(uint2*)(xhHi + rp * KP + u) = hv;
              *(uint2*)(xhLo + rp * KP + u) = lv;
            }
          } else {  // fallback: convert prefetched fp32 regs (r13 verbatim)
#pragma unroll
            for (int h2 = 0; h2 < 2; ++h2) {
#pragma unroll
              for (int q = 0; q < 4; ++q) {
                const float4 va = epr.f[h2 * 8 + 2 * q];
                const float4 vb = epr.f[h2 * 8 + 2 * q + 1];
                float xs[8] = {va.x, va.y, va.z, va.w, vb.x, vb.y, vb.z, vb.w};
                unsigned hw[4], lw[4];
#pragma unroll
                for (int m = 0; m < 4; ++m) {
                  unsigned short ha = f2bf(xs[2*m]);
                  unsigned short hc = f2bf(xs[2*m+1]);
                  unsigned short la = f2bf(xs[2*m]   - bf2f(ha));
                  unsigned short lc = f2bf(xs[2*m+1] - bf2f(hc));
                  hw[m] = (unsigned)ha | ((unsigned)hc << 16);
                  lw[m] = (unsigned)la | ((unsigned)lc << 16);
                }
                uint4 hv, lv;
                hv.x=hw[0]; hv.y=hw[1]; hv.z=hw[2]; hv.w=hw[3];
                lv.x=lw[0]; lv.y=lw[1]; lv.z=lw[2]; lv.w=lw[3];
                *(uint4*)(xhHi + rb * KP + ks + h2 * 32 + q * 8) = hv;
                *(uint4*)(xhLo + rb * KP + ks + h2 * 32 + q * 8) = lv;
              }
            }
          }
        } else {      // layer2 x = layer1 h: coalesced 32KB slab read
          const unsigned* slab = p.hpk + (size_t)((dl - 1) * 2 + par) * BH
                                       + (size_t)b0 * NH;
          stage_slab(slab, xhHi, xhLo, tid, 0);
        }
      } else {        // recurrent half, k in [512,1024)  (wave-pair 1, uniform)
        const unsigned* slab = p.hpk + (size_t)(dl * 2 + par) * BH
                                     + (size_t)b0 * NH;
        stage_slab(slab, xhHi, xhLo, tid - 128, 512);
      }
    }

    // prefetch next step's tokens (latency hides under MFMA+cell+barrier)
    int tk_nx = tk, tk_st_nx = tk_st, tk_pk_nx = tk_pk;
    if (j < SEQ) {
      int t_nx = layer ? j : (j + 1);
      if (t_nx > SEQ - 1) t_nx = SEQ - 1;
      const int to_nx = dir ? (SEQ - 1 - t_nx) : t_nx;
      tk_nx    = p.word[(size_t)to_nx * NB + b0 + cb];
      tk_st_nx = p.word[(size_t)to_nx * NB + b0 + rb];
      tk_pk_nx = p.word[(size_t)to_nx * NB + b0 + (rp & 15)];
    }

    // out-partner prefetch: FALLBACK (RMW) mode only; split mode never reads out
    float out_pf = 0.f;
    size_t oi = 0;
    int do_add = 0;
    if (act && layer == 1) {
      oi = (size_t)torig * BH + (size_t)(b0 + cb) * NH + uG;
      if (!p.bwd) {
        do_add = dir ? (torig < 512) : (torig > 511);
        if (do_add) out_pf = aldf(p.out + oi);
      }
    }

    __syncthreads();

    if (act) {
      // ---- K-split MFMA: wave wv sums kc in [8wv,8wv+8) for all 4 gates ----
      f32x4 aA[4], aBC[4];
#pragma unroll
      for (int gg = 0; gg < 4; ++gg) {
        aA[gg]  = (f32x4){0.f, 0.f, 0.f, 0.f};
        aBC[gg] = (f32x4){0.f, 0.f, 0.f, 0.f};
      }
      const unsigned short* bp = xhHi + (lane & 15) * KP + (lane >> 4) * 8;
      const unsigned short* bq = xhLo + (lane & 15) * KP + (lane >> 4) * 8;
#pragma unroll
      for (int kk = 0; kk < 8; ++kk) {
        const int kc = wv * 8 + kk;
        short8 bH = *(const short8*)(bp + kc * 32);
        short8 bL = *(const short8*)(bq + kc * 32);
#pragma unroll
        for (int gg = 0; gg < 4; ++gg) {
          aA[gg]  = __builtin_amdgcn_mfma_f32_16x16x32_bf16(aHi[gg*8+kk], bH, aA[gg],  0, 0, 0);
          aBC[gg] = __builtin_amdgcn_mfma_f32_16x16x32_bf16(aLo[gg*8+kk], bH, aBC[gg], 0, 0, 0);
          aBC[gg] = __builtin_amdgcn_mfma_f32_16x16x32_bf16(aHi[gg*8+kk], bL, aBC[gg], 0, 0, 0);
        }
      }
      // C/D (m89): col = lane&15 = batch, row = (lane>>4)*4 + reg = unit
#pragma unroll
      for (int gg = 0; gg < 4; ++gg) {
        f32x4 acc = aA[gg] + aBC[gg];
        *(f32x4*)&gl2[((wv * 4 + gg) * 16 + (lane & 15)) * 20 + (lane >> 4) * 4] = acc;
      }
    }
    __syncthreads();

    if (act) {
      // ---- fused cell: tree-sum the 4 waves' K-partials ----
#define GL2(w_,g_) gl2[(((w_) * 4 + (g_)) * 16 + cb) * 20 + cu]
      const float vi = ((GL2(0,0)+GL2(1,0)) + (GL2(2,0)+GL2(3,0))) + bi;
      const float vf = ((GL2(0,1)+GL2(1,1)) + (GL2(2,1)+GL2(3,1))) + bf_;
      const float vg = ((GL2(0,2)+GL2(1,2)) + (GL2(2,2)+GL2(3,2))) + bg;
      const float vo = ((GL2(0,3)+GL2(1,3)) + (GL2(2,3)+GL2(3,3))) + bo;
#undef GL2
      float cn = sigf(vf) * c_reg + sigf(vi) * tanhf(vg);
      float hn = sigf(vo) * tanhf(cn);
      if (tk == 1) { cn = c_reg; hn = h_reg; }
      c_reg = cn; h_reg = hn;
      const unsigned short hh = f2bf(hn);
      const unsigned short hl = f2bf(hn - bf2f(hh));
      const size_t hix = (size_t)(dl * 2 + (par ^ 1)) * BH + (size_t)(b0 + cb) * NH + uG;
      ast(p.hpk + hix, (unsigned)hh | ((unsigned)hl << 16));
      if (layer == 1) {
        if (p.bwd) {
          // split mode: store-only, no cross-direction coupling
          if (dir) astf(p.bwd + oi, 0.5f * hn);
          else     astf(p.out + oi, hn);
        } else {
          // fallback: ordered by the full device barrier; partner prefetched
          const float v = dir ? (0.5f * hn) : hn;
          astf(p.out + oi, do_add ? (out_pf + v) : v);
        }
      }
    }

    tk = tk_nx; tk_st = tk_st_nx; tk_pk = tk_pk_nx;

    // ---- flat leader device barrier (r6 topology, per-domain instance) ----
    __syncthreads();   // drains vmcnt -> all sc1 stores acked at coherence point
    if (tid == 0)
      ast(p.flags + (size_t)(dom * 64 + lid) * 16, (unsigned)(j + 1));

    // issue next-step emb loads NOW; they fly during the gen-wait
    if (j + 1 < SEQ) {
      if (use_pk) {
        const uint4* src = (const uint4*)(p.embP + (size_t)tk_pk * NH);
#pragma unroll
        for (int q = 0; q < 16; ++q) epr.u[q] = src[lp + q * 8];
      } else if (do_epf) {
        const float* e = p.emb + (size_t)tk_st * NH + ks;
#pragma unroll
        for (int q = 0; q < 16; ++q) epr.f[q] = *(const float4*)(e + q * 4);
      }
    }

    if (leader) {
      // gather: dsz single-writer lines, this block is the sole poller
      if (tid < dsz) {
        unsigned* f = p.flags + (size_t)(dom * 64 + tid) * 16;
        while (ald(f) < (unsigned)(j + 1)) __builtin_amdgcn_s_sleep(1);
      }
      __syncthreads();
      if (tid == 0) ast(genp, (unsigned)(j + 1));
    } else {
      if (tid < 64) {
        while (ald(genp) < (unsigned)(j + 1)) __builtin_amdgcn_s_sleep(1);
      }
      __syncthreads();
    }
  }

  // ---- epilogue: backward final carries bh1,bc1,bh2,bc2 ----
  if (dl == 2) {
    p.out[(size_t)SEQ * BH + 0 * (size_t)BH + (size_t)(b0 + cb) * NH + uG] = h_reg;
    p.out[(size_t)SEQ * BH + 1 * (size_t)BH + (size_t)(b0 + cb) * NH + uG] = c_reg;
  } else if (dl == 3) {
    p.out[(size_t)SEQ * BH + 2 * (size_t)BH + (size_t)(b0 + cb) * NH + uG] = h_reg;
    p.out[(size_t)SEQ * BH + 3 * (size_t)BH + (size_t)(b0 + cb) * NH + uG] = c_reg;
  }
}

extern "C" void kernel_launch(void* const* d_in, const int* in_sizes, int n_in,
                              void* d_out, int out_size, void* d_ws, size_t ws_size,
                              hipStream_t stream) {
  P p;
  p.word = (const int*)d_in[0];
  p.emb  = (const float*)d_in[1];
  for (int i = 0; i < 4; ++i) {
    p.Wih[i] = (const float*)d_in[2 + i * 4 + 0];
    p.Whh[i] = (const float*)d_in[2 + i * 4 + 1];
    p.bih[i] = (const float*)d_in[2 + i * 4 + 2];
    p.bhh[i] = (const float*)d_in[2 + i * 4 + 3];
  }
  unsigned char* ws = (unsigned char*)d_ws;
  p.flags = (unsigned*)ws;                       // 16 KB (256 x 64B slots)
  p.gen   = (unsigned*)(ws + 16384);             // 4 x 64B domain gen lines
  p.hpk   = (unsigned*)(ws + 16896);             // 512 KB packed h (moved past gen)
  const size_t embOff   = (size_t)1 << 20;       // 1 MB
  const size_t embBytes = (size_t)NV * NH * 4;   // 62.5 MB packed table
  p.embP = (ws_size >= embOff + embBytes) ? (const unsigned*)(ws + embOff)
                                          : nullptr;
  const size_t bwdOff   = (size_t)65 << 20;      // 65 MB
  const size_t bwdBytes = (size_t)SEQ * BH * 4;  // 64 MB
  const bool split = (ws_size >= bwdOff + bwdBytes) && (p.embP != nullptr);
  p.bwd = split ? (float*)(ws + bwdOff) : nullptr;
  p.out = (float*)d_out;

  // zero flags + gen + packed h (hpk now at 16896)
  hipMemsetAsync(d_ws, 0, 16896 + (size_t)8 * BH * 4, stream);

  if (p.embP) {
    // NV*NH = 16,384,000 elems, 8/thread -> 8000 blocks x 256
    hipLaunchKernelGGL(conv_embp, dim3(8000), dim3(256), 0, stream,
                       p.emb, (unsigned*)p.embP);
  }

  // used: 32*KP*2 + 4*4*16*20*4 = 86528 B; request 88 KB to keep 1 block/CU
  const int smem = 90112;
  hipFuncSetAttribute(reinterpret_cast<const void*>(enc_persist),
                      hipFuncAttributeMaxDynamicSharedMemorySize, smem);
  hipLaunchKernelGGL(enc_persist, dim3(256), dim3(256), smem, stream, p);

  if (split) {
    // out[i] += bwd[i] over SEQ*BH = 16,777,216 floats = 4 per thread
    hipLaunchKernelGGL(merge_out, dim3(16384), dim3(256), 0, stream,
                       p.out, p.bwd);
  }
}

// Round 13
// 4413.367 us; speedup vs baseline: 1.9252x; 1.0716x over previous
//
#include <hip/hip_runtime.h>
#include <math.h>

// EncoderRNN persistent kernel, round 18 = round 17 (PASSING, 4.73ms, split
// buffers + 4 domains) + ONE structural change: 1-HOP ALL-POLL barrier in
// split mode (+ a split-mode-only micro: out/bwd store deferred past the
// flag store, removing its ack from the pre-flag drain).
// r17 lesson: barrier is hop-LATENCY-bound (64 vs 256 width ~neutral) ->
// cut a hop. Failure taxonomy from r10/r11/r15: hot (multi-writer) lines
// regress; single-writer lines with many pollers (r6's gen: 1W/255P) are
// proven fine. The 1-hop form: each domain block polls its domain's 64
// single-writer 64B-stride flag lines (tid<64, one line per lane) -- all
// lines in the proven 1W/NP class. This is r7's barrier, whose correctness
// failure is now explained by the out-RMW 1-step skew margin at torig=
// 511/512 -- removed BY CONSTRUCTION in split mode (store-only outputs,
// stream-ordered merge kernel). RAW: producer flag j => its h drained.
// WAR: poll pass => all 64 domain blocks (incl. all consumers) posted j =>
// step-j reads done. Fallback (no ws): r6 2-hop leader barrier verbatim.
// Predicted: pass, absmax 0.0001220703, dur 4.73 -> ~3.9-4.3ms,
// MfmaUtil ~15.5, VALUBusy ~23, bank-conflict ~1.34e8, FETCH/WRITE same.
// Pre-registered: fail => domains unsafe, permanent r17 revert; regress =>
// poll volume was r10's real mechanism, revert to 2-hop.

#define SEQ 1024
#define NB 32
#define NH 512
#define BH (NB*NH)
#define NV 32000
#define KP 1032   // LDS row stride in shorts = 2064 B (odd 16B slots)

typedef __attribute__((ext_vector_type(8))) short short8;
typedef __attribute__((ext_vector_type(4))) float f32x4;
typedef unsigned long long u64;

struct P {
  const int*   word;
  const float* emb;
  const float* Wih[4];   // dl = dir*2+layer: 0=fwd1,1=fwd2,2=bwd1,3=bwd2
  const float* Whh[4];
  const float* bih[4];
  const float* bhh[4];
  unsigned* flags;       // 256 slots, stride 16 u32 (one 64B line each)
  unsigned* gen;         // single 64B line (fallback 2-hop only)
  unsigned* hpk;         // [4 dl][2 par][NB][NH] u32 = (bf16hi | bf16lo<<16)
  const unsigned* embP;  // [NV][NH] u32 packed (hh | hl<<16), or null
  float* out;
  float* bwd;            // bwd-direction partial buffer (or null = fallback)
};

__device__ __forceinline__ unsigned short f2bf(float x) {
  unsigned u = __float_as_uint(x);
  return (unsigned short)((u + 0x7fffu + ((u >> 16) & 1u)) >> 16);  // RNE
}
__device__ __forceinline__ float bf2f(unsigned short b) {
  return __uint_as_float(((unsigned)b) << 16);
}
__device__ __forceinline__ float sigf(float x) { return 1.0f / (1.0f + expf(-x)); }

__device__ __forceinline__ unsigned ald(const unsigned* p_) {
  return __hip_atomic_load((unsigned*)p_, __ATOMIC_RELAXED, __HIP_MEMORY_SCOPE_AGENT);
}
__device__ __forceinline__ u64 ald64(const u64* p_) {
  return __hip_atomic_load((u64*)p_, __ATOMIC_RELAXED, __HIP_MEMORY_SCOPE_AGENT);
}
__device__ __forceinline__ void ast(unsigned* p_, unsigned v) {
  __hip_atomic_store(p_, v, __ATOMIC_RELAXED, __HIP_MEMORY_SCOPE_AGENT);
}
__device__ __forceinline__ float aldf(const float* p_) {
  return __hip_atomic_load((float*)p_, __ATOMIC_RELAXED, __HIP_MEMORY_SCOPE_AGENT);
}
__device__ __forceinline__ void astf(float* p_, float v) {
  __hip_atomic_store(p_, v, __ATOMIC_RELAXED, __HIP_MEMORY_SCOPE_AGENT);
}

// Coalesced slab stage (r13/r14 proven): wave-PAIR (128 lanes) reads a 32KB
// contiguous slab (16 rows x 512 packed u32) -> bf16 hi/lo planes in LDS.
__device__ __forceinline__ void stage_slab(const unsigned* slab,
                                           unsigned short* xhHi,
                                           unsigned short* xhLo,
                                           int Lpair, int koff) {
  const u64* s64 = (const u64*)slab;
  u64 A[32];
#pragma unroll
  for (int q = 0; q < 32; ++q) A[q] = ald64(s64 + Lpair + q * 128);
#pragma unroll
  for (int q = 0; q < 32; ++q) {
    const int r = q >> 1;                    // batch row 0..15
    const int c = (q & 1) * 128 + Lpair;     // u64 col 0..255 -> units 2c,2c+1
    const unsigned w0 = (unsigned)A[q];
    const unsigned w1 = (unsigned)(A[q] >> 32);
    *(unsigned*)(xhHi + r * KP + koff + 2 * c) = (w0 & 0xffffu) | (w1 << 16);
    *(unsigned*)(xhLo + r * KP + koff + 2 * c) = (w0 >> 16)     | (w1 & 0xffff0000u);
  }
}

// one-time embedding fp32 -> packed u32 (hh | hl<<16); identical RNE math
__global__ void conv_embp(const float* __restrict__ e,
                          unsigned* __restrict__ pk) {
  const size_t i = ((size_t)blockIdx.x * 256 + threadIdx.x) * 8;
  float4 a = *(const float4*)(e + i);
  float4 b = *(const float4*)(e + i + 4);
  float xs[8] = {a.x, a.y, a.z, a.w, b.x, b.y, b.z, b.w};
  unsigned o[8];
#pragma unroll
  for (int q = 0; q < 8; ++q) {
    unsigned short hb = f2bf(xs[q]);
    unsigned short lb = f2bf(xs[q] - bf2f(hb));
    o[q] = (unsigned)hb | ((unsigned)lb << 16);
  }
  uint4 v0, v1;
  v0.x=o[0]; v0.y=o[1]; v0.z=o[2]; v0.w=o[3];
  v1.x=o[4]; v1.y=o[5]; v1.z=o[6]; v1.w=o[7];
  *(uint4*)(pk + i)     = v0;
  *(uint4*)(pk + i + 4) = v1;
}

// post-pass: out[i] += bwd[i] over SEQ*BH. Same two-term fp32 add as the
// fallback's ordered RMW (add commutes bitwise) -> absmax identical.
__global__ void merge_out(float* __restrict__ out, const float* __restrict__ bwd) {
  const size_t i = ((size_t)blockIdx.x * 256 + threadIdx.x) * 4;
  float4 a = *(const float4*)(out + i);
  const float4 b = *(const float4*)(bwd + i);
  a.x += b.x; a.y += b.y; a.z += b.z; a.w += b.w;
  *(float4*)(out + i) = a;
}

__global__ __launch_bounds__(256, 1) void enc_persist(P p) {
  extern __shared__ unsigned short smem[];
  unsigned short* xhHi = smem;              // [16][KP]
  unsigned short* xhLo = smem + 16 * KP;    // [16][KP]
  float* gl2 = (float*)(smem + 32 * KP);    // [4 wv][4 gate][16 batch][20] fp32

  const int tid  = threadIdx.x;
  const int bid  = blockIdx.x;
  const int dl   = bid >> 6;
  const int dir  = dl >> 1, layer = dl & 1;
  const int r6   = bid & 63;
  const int u0   = (r6 >> 1) * 16;   // 32 unit-groups of 16
  const int b0   = (r6 & 1) * 16;    // 2 batch-halves of 16
  const int lane = tid & 63, wv = tid >> 6;   // wave wv owns kc in [8wv, 8wv+8)

  // barrier domain (split mode): (dir, batch-half) = exact dependency closure
  const int dom  = p.bwd ? (dir * 2 + (r6 & 1)) : 0;
  const int lid  = p.bwd ? (layer * 32 + (r6 >> 1)) : bid;

  // ---- prologue: W fragments (bf16 hi/lo) for all 4 gates, this wave's K ----
  short8 aHi[32], aLo[32];   // index gg*8+kk
  {
    const int kg = (lane >> 4) * 8;
#pragma unroll
    for (int gg = 0; gg < 4; ++gg) {
      const int gr = gg * 512 + u0 + (lane & 15);   // global gate row
      const float* Wi = p.Wih[dl] + (size_t)gr * NH;
      const float* Wh = p.Whh[dl] + (size_t)gr * NH;
#pragma unroll
      for (int kk = 0; kk < 8; ++kk) {
        const int k0 = (wv * 8 + kk) * 32 + kg;
        const float* s = (k0 < 512) ? (Wi + k0) : (Wh + (k0 - 512));
        float4 v0 = *(const float4*)s;
        float4 v1 = *(const float4*)(s + 4);
        float xs[8] = {v0.x, v0.y, v0.z, v0.w, v1.x, v1.y, v1.z, v1.w};
        short8 h8, l8;
#pragma unroll
        for (int q = 0; q < 8; ++q) {
          unsigned short hb = f2bf(xs[q]);
          h8[q] = (short)hb;
          l8[q] = (short)f2bf(xs[q] - bf2f(hb));
        }
        aHi[gg * 8 + kk] = h8; aLo[gg * 8 + kk] = l8;
      }
    }
  }

  // cell thread mapping: cb = batch-local (tid>>4), cu = unit (tid&15)
  const int cu = tid & 15, cb = tid >> 4;
  const int uG = u0 + cu;
  const float bi  = p.bih[dl][uG]        + p.bhh[dl][uG];
  const float bf_ = p.bih[dl][512 + uG]  + p.bhh[dl][512 + uG];
  const float bg  = p.bih[dl][1024 + uG] + p.bhh[dl][1024 + uG];
  const float bo  = p.bih[dl][1536 + uG] + p.bhh[dl][1536 + uG];

  float c_reg = 0.f, h_reg = 0.f;

  // fallback emb staging mapping (embP null): rb = row, sr = k-slice
  const int sr = tid >> 4;
  const int rb = tid & 15;
  const int ks = sr * 64;

  // packed emb staging mapping (waves 0-1): rp = row (tid>>3), lp = tid&7
  const int rp = tid >> 3;     // 0..15 for tid<128
  const int lp = tid & 7;

  int tk, tk_st, tk_pk;
  {
    const int to0 = dir ? (SEQ - 1) : 0;
    tk    = p.word[(size_t)to0 * NB + b0 + cb];   // cell mask token
    tk_st = p.word[(size_t)to0 * NB + b0 + rb];   // fallback staging token
    tk_pk = p.word[(size_t)to0 * NB + b0 + (rp & 15)]; // packed staging token
  }

  const bool use_pk = (layer == 0) && (tid < 128) && (p.embP != nullptr);
  const bool do_epf = (layer == 0) && (sr < 8) && (p.embP == nullptr);
  union { float4 f[16]; uint4 u[16]; } epr;
  if (use_pk) {   // prologue prefetch for j=0 (packed)
    const uint4* src = (const uint4*)(p.embP + (size_t)tk_pk * NH);
#pragma unroll
    for (int q = 0; q < 16; ++q) epr.u[q] = src[lp + q * 8];
  } else if (do_epf) {  // prologue prefetch for j=0 (fallback fp32)
    const float* e = p.emb + (size_t)tk_st * NH + ks;
#pragma unroll
    for (int q = 0; q < 16; ++q) epr.f[q] = *(const float4*)(e + q * 4);
  }

  for (int j = 0; j <= SEQ; ++j) {
    const int act = layer ? (j >= 1) : (j < SEQ);
    const int t = layer ? (j - 1) : j;
    const int torig = dir ? (SEQ - 1 - t) : t;
    const int par = j & 1;

    // deferred out store slots (split mode): issued after the flag store
    float out_v = 0.f;
    float* out_tgt = nullptr;

    if (act) {
      // ---- stage one row-slice of [x(512);h(512)] bf16 hi/lo into LDS ----
      if (wv < 2) {   // x-part, k in [0,512)  (wave-pair 0, uniform)
        if (layer == 0) {
          if (p.embP) {
            // unpack prefetched packed-emb registers -> LDS (bit-exact)
#pragma unroll
            for (int q = 0; q < 16; ++q) {
              const uint4 w = epr.u[q];
              const int u = 4 * (lp + q * 8);   // unit 0..508
              uint2 hv, lv;
              hv.x = (w.x & 0xffffu) | (w.y << 16);
              hv.y = (w.z & 0xffffu) | (w.w << 16);
              lv.x = (w.x >> 16)     | (w.y & 0xffff0000u);
              lv.y = (w.z >> 16)     | (w.w & 0xffff0000u);
              *(uint2*)(xhHi + rp * KP + u) = hv;
              *(uint2*)(xhLo + rp * KP + u) = lv;
            }
          } else {  // fallback: convert prefetched fp32 regs (r13 verbatim)
#pragma unroll
            for (int h2 = 0; h2 < 2; ++h2) {
#pragma unroll
              for (int q = 0; q < 4; ++q) {
                const float4 va = epr.f[h2 * 8 + 2 * q];
                const float4 vb = epr.f[h2 * 8 + 2 * q + 1];
                float xs[8] = {va.x, va.y, va.z, va.w, vb.x, vb.y, vb.z, vb.w};
                unsigned hw[4], lw[4];
#pragma unroll
                for (int m = 0; m < 4; ++m) {
                  unsigned short ha = f2bf(xs[2*m]);
                  unsigned short hc = f2bf(xs[2*m+1]);
                  unsigned short la = f2bf(xs[2*m]   - bf2f(ha));
                  unsigned short lc = f2bf(xs[2*m+1] - bf2f(hc));
                  hw[m] = (unsigned)ha | ((unsigned)hc << 16);
                  lw[m] = (unsigned)la | ((unsigned)lc << 16);
                }
                uint4 hv, lv;
                hv.x=hw[0]; hv.y=hw[1]; hv.z=hw[2]; hv.w=hw[3];
                lv.x=lw[0]; lv.y=lw[1]; lv.z=lw[2]; lv.w=lw[3];
                *(uint4*)(xhHi + rb * KP + ks + h2 * 32 + q * 8) = hv;
                *(uint4*)(xhLo + rb * KP + ks + h2 * 32 + q * 8) = lv;
              }
            }
          }
        } else {      // layer2 x = layer1 h: coalesced 32KB slab read
          const unsigned* slab = p.hpk + (size_t)((dl - 1) * 2 + par) * BH
                                       + (size_t)b0 * NH;
          stage_slab(slab, xhHi, xhLo, tid, 0);
        }
      } else {        // recurrent half, k in [512,1024)  (wave-pair 1, uniform)
        const unsigned* slab = p.hpk + (size_t)(dl * 2 + par) * BH
                                     + (size_t)b0 * NH;
        stage_slab(slab, xhHi, xhLo, tid - 128, 512);
      }
    }

    // prefetch next step's tokens (latency hides under MFMA+cell+barrier)
    int tk_nx = tk, tk_st_nx = tk_st, tk_pk_nx = tk_pk;
    if (j < SEQ) {
      int t_nx = layer ? j : (j + 1);
      if (t_nx > SEQ - 1) t_nx = SEQ - 1;
      const int to_nx = dir ? (SEQ - 1 - t_nx) : t_nx;
      tk_nx    = p.word[(size_t)to_nx * NB + b0 + cb];
      tk_st_nx = p.word[(size_t)to_nx * NB + b0 + rb];
      tk_pk_nx = p.word[(size_t)to_nx * NB + b0 + (rp & 15)];
    }

    // out-partner prefetch: FALLBACK (RMW) mode only; split mode never reads out
    float out_pf = 0.f;
    size_t oi = 0;
    int do_add = 0;
    if (act && layer == 1) {
      oi = (size_t)torig * BH + (size_t)(b0 + cb) * NH + uG;
      if (!p.bwd) {
        do_add = dir ? (torig < 512) : (torig > 511);
        if (do_add) out_pf = aldf(p.out + oi);
      }
    }

    __syncthreads();

    if (act) {
      // ---- K-split MFMA: wave wv sums kc in [8wv,8wv+8) for all 4 gates ----
      f32x4 aA[4], aBC[4];
#pragma unroll
      for (int gg = 0; gg < 4; ++gg) {
        aA[gg]  = (f32x4){0.f, 0.f, 0.f, 0.f};
        aBC[gg] = (f32x4){0.f, 0.f, 0.f, 0.f};
      }
      const unsigned short* bp = xhHi + (lane & 15) * KP + (lane >> 4) * 8;
      const unsigned short* bq = xhLo + (lane & 15) * KP + (lane >> 4) * 8;
#pragma unroll
      for (int kk = 0; kk < 8; ++kk) {
        const int kc = wv * 8 + kk;
        short8 bH = *(const short8*)(bp + kc * 32);
        short8 bL = *(const short8*)(bq + kc * 32);
#pragma unroll
        for (int gg = 0; gg < 4; ++gg) {
          aA[gg]  = __builtin_amdgcn_mfma_f32_16x16x32_bf16(aHi[gg*8+kk], bH, aA[gg],  0, 0, 0);
          aBC[gg] = __builtin_amdgcn_mfma_f32_16x16x32_bf16(aLo[gg*8+kk], bH, aBC[gg], 0, 0, 0);
          aBC[gg] = __builtin_amdgcn_mfma_f32_16x16x32_bf16(aHi[gg*8+kk], bL, aBC[gg], 0, 0, 0);
        }
      }
      // C/D (m89): col = lane&15 = batch, row = (lane>>4)*4 + reg = unit
#pragma unroll
      for (int gg = 0; gg < 4; ++gg) {
        f32x4 acc = aA[gg] + aBC[gg];
        *(f32x4*)&gl2[((wv * 4 + gg) * 16 + (lane & 15)) * 20 + (lane >> 4) * 4] = acc;
      }
    }
    __syncthreads();

    if (act) {
      // ---- fused cell: tree-sum the 4 waves' K-partials ----
#define GL2(w_,g_) gl2[(((w_) * 4 + (g_)) * 16 + cb) * 20 + cu]
      const float vi = ((GL2(0,0)+GL2(1,0)) + (GL2(2,0)+GL2(3,0))) + bi;
      const float vf = ((GL2(0,1)+GL2(1,1)) + (GL2(2,1)+GL2(3,1))) + bf_;
      const float vg = ((GL2(0,2)+GL2(1,2)) + (GL2(2,2)+GL2(3,2))) + bg;
      const float vo = ((GL2(0,3)+GL2(1,3)) + (GL2(2,3)+GL2(3,3))) + bo;
#undef GL2
      float cn = sigf(vf) * c_reg + sigf(vi) * tanhf(vg);
      float hn = sigf(vo) * tanhf(cn);
      if (tk == 1) { cn = c_reg; hn = h_reg; }
      c_reg = cn; h_reg = hn;
      const unsigned short hh = f2bf(hn);
      const unsigned short hl = f2bf(hn - bf2f(hh));
      const size_t hix = (size_t)(dl * 2 + (par ^ 1)) * BH + (size_t)(b0 + cb) * NH + uG;
      ast(p.hpk + hix, (unsigned)hh | ((unsigned)hl << 16));
      if (layer == 1) {
        if (p.bwd) {
          // split mode: defer store past the flag (no in-kernel reader;
          // visibility via kernel-end drain + stream order before merge_out)
          out_v = dir ? (0.5f * hn) : hn;
          out_tgt = (dir ? p.bwd : p.out) + oi;
        } else {
          // fallback: ordered by the full device barrier; partner prefetched
          const float v = dir ? (0.5f * hn) : hn;
          astf(p.out + oi, do_add ? (out_pf + v) : v);
        }
      }
    }

    tk = tk_nx; tk_st = tk_st_nx; tk_pk = tk_pk_nx;

    // ---- device barrier ----
    __syncthreads();   // drains vmcnt -> hpk stores acked at coherence point
    if (tid == 0)
      ast(p.flags + (size_t)(dom * 64 + lid) * 16, (unsigned)(j + 1));

    // deferred out/bwd store: overlaps the poll wait, skips the drain
    if (out_tgt) astf(out_tgt, out_v);

    // issue next-step emb loads NOW; they fly during the poll
    if (j + 1 < SEQ) {
      if (use_pk) {
        const uint4* src = (const uint4*)(p.embP + (size_t)tk_pk * NH);
#pragma unroll
        for (int q = 0; q < 16; ++q) epr.u[q] = src[lp + q * 8];
      } else if (do_epf) {
        const float* e = p.emb + (size_t)tk_st * NH + ks;
#pragma unroll
        for (int q = 0; q < 16; ++q) epr.f[q] = *(const float4*)(e + q * 4);
      }
    }

    if (p.bwd) {
      // 1-hop all-poll: 64 single-writer lines (1W/63P class, proven by gen)
      if (tid < 64) {
        unsigned* f = p.flags + (size_t)(dom * 64 + tid) * 16;
        while (ald(f) < (unsigned)(j + 1)) __builtin_amdgcn_s_sleep(1);
      }
      __syncthreads();
    } else {
      // fallback: r6 2-hop leader barrier over 256 blocks
      if (bid == 0) {
        unsigned* f = p.flags + (size_t)tid * 16;
        while (ald(f) < (unsigned)(j + 1)) __builtin_amdgcn_s_sleep(1);
        __syncthreads();
        if (tid == 0) ast(p.gen, (unsigned)(j + 1));
      } else {
        if (tid < 64) {
          while (ald(p.gen) < (unsigned)(j + 1)) __builtin_amdgcn_s_sleep(1);
        }
        __syncthreads();
      }
    }
  }

  // ---- epilogue: backward final carries bh1,bc1,bh2,bc2 ----
  if (dl == 2) {
    p.out[(size_t)SEQ * BH + 0 * (size_t)BH + (size_t)(b0 + cb) * NH + uG] = h_reg;
    p.out[(size_t)SEQ * BH + 1 * (size_t)BH + (size_t)(b0 + cb) * NH + uG] = c_reg;
  } else if (dl == 3) {
    p.out[(size_t)SEQ * BH + 2 * (size_t)BH + (size_t)(b0 + cb) * NH + uG] = h_reg;
    p.out[(size_t)SEQ * BH + 3 * (size_t)BH + (size_t)(b0 + cb) * NH + uG] = c_reg;
  }
}

extern "C" void kernel_launch(void* const* d_in, const int* in_sizes, int n_in,
                              void* d_out, int out_size, void* d_ws, size_t ws_size,
                              hipStream_t stream) {
  P p;
  p.word = (const int*)d_in[0];
  p.emb  = (const float*)d_in[1];
  for (int i = 0; i < 4; ++i) {
    p.Wih[i] = (const float*)d_in[2 + i * 4 + 0];
    p.Whh[i] = (const float*)d_in[2 + i * 4 + 1];
    p.bih[i] = (const float*)d_in[2 + i * 4 + 2];
    p.bhh[i] = (const float*)d_in[2 + i * 4 + 3];
  }
  unsigned char* ws = (unsigned char*)d_ws;
  p.flags = (unsigned*)ws;                       // 16 KB (256 x 64B slots)
  p.gen   = (unsigned*)(ws + 16384);             // 64B (fallback only)
  p.hpk   = (unsigned*)(ws + 16896);             // 512 KB packed h
  const size_t embOff   = (size_t)1 << 20;       // 1 MB
  const size_t embBytes = (size_t)NV * NH * 4;   // 62.5 MB packed table
  p.embP = (ws_size >= embOff + embBytes) ? (const unsigned*)(ws + embOff)
                                          : nullptr;
  const size_t bwdOff   = (size_t)65 << 20;      // 65 MB
  const size_t bwdBytes = (size_t)SEQ * BH * 4;  // 64 MB
  const bool split = (ws_size >= bwdOff + bwdBytes) && (p.embP != nullptr);
  p.bwd = split ? (float*)(ws + bwdOff) : nullptr;
  p.out = (float*)d_out;

  // zero flags + gen + packed h
  hipMemsetAsync(d_ws, 0, 16896 + (size_t)8 * BH * 4, stream);

  if (p.embP) {
    // NV*NH = 16,384,000 elems, 8/thread -> 8000 blocks x 256
    hipLaunchKernelGGL(conv_embp, dim3(8000), dim3(256), 0, stream,
                       p.emb, (unsigned*)p.embP);
  }

  // used: 32*KP*2 + 4*4*16*20*4 = 86528 B; request 88 KB to keep 1 block/CU
  const int smem = 90112;
  hipFuncSetAttribute(reinterpret_cast<const void*>(enc_persist),
                      hipFuncAttributeMaxDynamicSharedMemorySize, smem);
  hipLaunchKernelGGL(enc_persist, dim3(256), dim3(256), smem, stream, p);

  if (split) {
    // out[i] += bwd[i] over SEQ*BH = 16,777,216 floats = 4 per thread
    hipLaunchKernelGGL(merge_out, dim3(16384), dim3(256), 0, stream,
                       p.out, p.bwd);
  }
}